// Round 3
// baseline (578.247 us; speedup 1.0000x reference)
//
#include <hip/hip_runtime.h>
#include <hip/hip_bf16.h>

typedef unsigned short u16;
typedef __attribute__((ext_vector_type(8))) __bf16 bf16x8;
typedef __attribute__((ext_vector_type(4))) float f32x4;
typedef __attribute__((ext_vector_type(16))) float f32x16;

#define DIN 4096
#define DOUT 4096
#define MROWS 8192

__device__ __forceinline__ u16 f2bf(float f) {
  unsigned int u = __float_as_uint(f);
  u += 0x7fffu + ((u >> 16) & 1u);   // RNE; inputs are finite randoms
  return (u16)(u >> 16);
}

__device__ __forceinline__ void gl2lds16(const void* g, void* l) {
  __builtin_amdgcn_global_load_lds(
      (const __attribute__((address_space(1))) unsigned int*)g,
      (__attribute__((address_space(3))) unsigned int*)l, 16, 0, 0);
}

// ---------------------------------------------------------------------------
// Kernel 1: fused prep (unchanged from round 2; prep was shown non-limiting).
__global__ __launch_bounds__(256) void prep_all(
    const float* __restrict__ x, const float* __restrict__ W,
    const float* __restrict__ up, const float* __restrict__ route,
    const float* __restrict__ down,
    u16* __restrict__ Xb, u16* __restrict__ Wb,
    u16* __restrict__ Ub, u16* __restrict__ Wt) {
  const size_t NT = 2048 * 256;
  const size_t gtid = (size_t)blockIdx.x * 256 + threadIdx.x;

  if (gtid < 4096) {
    const int n = (int)gtid;
    union { u16 us[32]; uint4 q[4]; } o;
    #pragma unroll
    for (int c = 0; c < 32; ++c) o.us[c] = f2bf(up[(size_t)c * DOUT + n]);
    uint4* dst = (uint4*)(Ub + (size_t)n * 32);
    #pragma unroll
    for (int q = 0; q < 4; ++q) dst[q] = o.q[q];
  }

  if (gtid < 49152) {
    const int c = (int)(gtid >> 10);
    const int k0 = ((int)gtid & 1023) * 4;
    const float* route3 = route + 3 * DIN * 5;  // lora_route[3]
    float v[4];
    #pragma unroll
    for (int j = 0; j < 4; ++j) {
      int k = k0 + j;
      float f;
      if (c < 3)       f = route3[(size_t)k * 5 + c];
      else if (c < 35) f = down[(size_t)((c - 3) >> 3) * DIN * 8 + (size_t)k * 8 + ((c - 3) & 7)];
      else             f = 0.f;
      v[j] = f;
    }
    ushort4 o;
    o.x = f2bf(v[0]); o.y = f2bf(v[1]); o.z = f2bf(v[2]); o.w = f2bf(v[3]);
    *(ushort4*)(Wt + (size_t)c * DIN + k0) = o;
  }

  #pragma unroll 4
  for (int it = 0; it < 16; ++it) {
    size_t i = gtid + (size_t)it * NT;
    float4 v = ((const float4*)x)[i];
    ushort4 o;
    o.x = f2bf(v.x); o.y = f2bf(v.y); o.z = f2bf(v.z); o.w = f2bf(v.w);
    ((ushort4*)Xb)[i] = o;
  }

  #pragma unroll 4
  for (int it = 0; it < 8; ++it) {
    size_t i = gtid + (size_t)it * NT;
    float4 v = ((const float4*)W)[i];
    ushort4 o;
    o.x = f2bf(v.x); o.y = f2bf(v.y); o.z = f2bf(v.z); o.w = f2bf(v.w);
    ((ushort4*)Wb)[i] = o;
  }
}

// ---------------------------------------------------------------------------
// Kernel 2: MFMA tall-skinny GEMM Pw[split][8192][48] = Xb . Wt^T (unchanged).
__global__ __launch_bounds__(256) void coeffgemm(
    const u16* __restrict__ Xb, const u16* __restrict__ Wt,
    float* __restrict__ Pw) {
  __shared__ __align__(16) u16 As[64 * 64];
  __shared__ __align__(16) u16 Bs[48 * 64];
  const int tid = threadIdx.x;
  const int m0 = blockIdx.x * 64;
  const int kb = blockIdx.y * 512;
  const int lane = tid & 63;
  const int w = tid >> 6;
  const int wr = w * 16;
  const int fm = lane & 15;
  const int xr = fm & 7;
  const int qd = lane >> 4;

  f32x4 acc[3];
  #pragma unroll
  for (int j = 0; j < 3; ++j) acc[j] = (f32x4){0.f, 0.f, 0.f, 0.f};

  const int arow = tid >> 3;
  const int ac = ((tid & 7) ^ (arow & 7)) * 8;
  const u16* gA = Xb + (size_t)(m0 + arow) * DIN + kb + ac;
  const u16* gBt = Wt + (size_t)arow * DIN + kb + ac;

  for (int kc = 0; kc < 512; kc += 64) {
    gl2lds16(gBt + kc, Bs + tid * 8);
    if (tid < 128)
      gl2lds16(gBt + 32 * DIN + kc, Bs + (256 + tid) * 8);
    gl2lds16(gA + kc, As + tid * 8);
    gl2lds16(gA + 32 * DIN + kc, As + (256 + tid) * 8);
    __syncthreads();
    #pragma unroll
    for (int kk = 0; kk < 64; kk += 32) {
      const int q = (kk >> 3) + qd;
      bf16x8 af = *(const bf16x8*)(As + (wr + fm) * 64 + ((q ^ xr) << 3));
      bf16x8 bfr[3];
      #pragma unroll
      for (int j = 0; j < 3; ++j)
        bfr[j] = *(const bf16x8*)(Bs + (j * 16 + fm) * 64 + ((q ^ xr) << 3));
      #pragma unroll
      for (int j = 0; j < 3; ++j)
        acc[j] = __builtin_amdgcn_mfma_f32_16x16x32_bf16(af, bfr[j], acc[j], 0, 0, 0);
    }
    __syncthreads();
  }
  const int em = (lane >> 4) * 4;
  const int en = lane & 15;
  const size_t pbase = (size_t)blockIdx.y * MROWS;
  #pragma unroll
  for (int j = 0; j < 3; ++j)
    #pragma unroll
    for (int r = 0; r < 4; ++r)
      Pw[(pbase + m0 + wr + em + r) * 48 + j * 16 + en] = acc[j][r];
}

// ---------------------------------------------------------------------------
// Kernel 3: reduce 8 K-split partials + softmax gate -> Cb (unchanged).
__global__ __launch_bounds__(256) void reduce_coeff(const float* __restrict__ Pw,
                                                    u16* __restrict__ Cb) {
  const int tid = threadIdx.x;
  const int rl = tid >> 2;
  const int cg = tid & 3;
  const int m = blockIdx.x * 64 + rl;
  const int lane = tid & 63;

  float s[12];
  #pragma unroll
  for (int q = 0; q < 12; ++q) s[q] = 0.f;
  for (int sp = 0; sp < 8; ++sp) {
    const float4* p = (const float4*)(Pw + ((size_t)sp * MROWS + m) * 48 + cg * 12);
    #pragma unroll
    for (int q = 0; q < 3; ++q) {
      float4 v = p[q];
      s[q * 4 + 0] += v.x; s[q * 4 + 1] += v.y;
      s[q * 4 + 2] += v.z; s[q * 4 + 3] += v.w;
    }
  }
  const int src = lane & ~3;
  const float L0 = __shfl(s[0], src);
  const float L1 = __shfl(s[1], src);
  const float L2 = __shfl(s[2], src);
  const float mx = fmaxf(L0, fmaxf(L1, L2));
  const float e0 = __expf(L0 - mx), e1 = __expf(L1 - mx), e2 = __expf(L2 - mx);
  const float inv = 1.f / (e0 + e1 + e2);
  const float om0 = e0 * inv, om1 = e1 * inv, om2 = e2 * inv;
  #pragma unroll
  for (int j = 0; j < 12; ++j) {
    const int G = cg * 12 + j;
    if (G >= 3 && G < 35) {
      const float wgt = (G < 11) ? om0 : (G < 19) ? om1 : (G < 27) ? om2 : 1.f;
      Cb[(size_t)m * 32 + (G - 3)] = f2bf(s[j] * wgt);
    }
  }
}

// ---------------------------------------------------------------------------
// Kernel 4: out = Xb @ Wb^T + Cb @ Ub^T.
// Same 256x256 / 8-wave / 4-phase-per-K-tile / counted-vmcnt(4) skeleton as
// round 1-2, but compute ported to mfma_f32_32x32x16_bf16 (2495 TF ceiling vs
// 2075; 8 inst/phase vs 16). LDS layout and staging ledger UNCHANGED.
// 32x32 A-frag: lane reads row32=lane&31, k=(lane>>5)*8 within each K=16 step;
// in the packed layout (row r, k8) -> lrow=r>>1, c=( r&1)*4+k8, c'=c^(lrow&7),
// u16 = lrow*64+c'*8. Consecutive-8-lane groups cover all 8 bank quads ->
// conflict-free (verified by enumeration, matches the measured-0 16x16 case).
// C/D layout (32x32): col=lane&31, row=(reg&3)+8*(reg>>2)+4*(lane>>5).

#define MF32(a, b, c) __builtin_amdgcn_mfma_f32_32x32x16_bf16(a, b, c, 0, 0, 0)

#define VM4 asm volatile("s_waitcnt vmcnt(4)" ::: "memory")
#define VM0 asm volatile("s_waitcnt vmcnt(0)" ::: "memory")

#define STA(REG, KOFF) { const u16* s_ = gA + (KOFF); \
  gl2lds16(s_, dA + (REG) * 8192); \
  gl2lds16(s_ + 128 * 4096, dA + (REG) * 8192 + 4096); }
#define STB(REG, KOFF) { const u16* s_ = gB + (KOFF); \
  gl2lds16(s_, dB + (REG) * 8192); \
  gl2lds16(s_ + 128 * 4096, dB + (REG) * 8192 + 4096); }
#define STC { const u16* s_ = Cb + (size_t)(m0 + gr1) * 32 + kc1; \
  gl2lds16(s_, dA); gl2lds16(s_ + 128 * 32, dA + 4096); }
#define STU { const u16* s_ = Ub + (size_t)(n0 + gr1) * 32 + kc1; \
  gl2lds16(s_, dB); gl2lds16(s_ + 128 * 32, dB + 4096); }

#define PH32(REG, IH, LOADB, ISSUE, VMX) { \
  const u16* ap_ = sm + (REG) * 8192 + wmoff + (IH) * 2048 + arl64; \
  bf16x8 a00 = *(const bf16x8*)(ap_ + cof0); \
  bf16x8 a01 = *(const bf16x8*)(ap_ + cof1); \
  bf16x8 a10 = *(const bf16x8*)(ap_ + 1024 + cof0); \
  bf16x8 a11 = *(const bf16x8*)(ap_ + 1024 + cof1); \
  if (LOADB) { \
    const u16* bp_ = sm + 32768 + (REG) * 8192 + wnoff + arl64; \
    b00 = *(const bf16x8*)(bp_ + cof0); \
    b01 = *(const bf16x8*)(bp_ + cof1); \
    b10 = *(const bf16x8*)(bp_ + 1024 + cof0); \
    b11 = *(const bf16x8*)(bp_ + 1024 + cof1); \
  } \
  ISSUE; \
  asm volatile("" ::: "memory"); \
  __builtin_amdgcn_s_barrier(); \
  __builtin_amdgcn_s_setprio(1); \
  acc[(IH)*2+0][0] = MF32(a00, b00, acc[(IH)*2+0][0]); \
  acc[(IH)*2+0][1] = MF32(a00, b10, acc[(IH)*2+0][1]); \
  acc[(IH)*2+1][0] = MF32(a10, b00, acc[(IH)*2+1][0]); \
  acc[(IH)*2+1][1] = MF32(a10, b10, acc[(IH)*2+1][1]); \
  acc[(IH)*2+0][0] = MF32(a01, b01, acc[(IH)*2+0][0]); \
  acc[(IH)*2+0][1] = MF32(a01, b11, acc[(IH)*2+0][1]); \
  acc[(IH)*2+1][0] = MF32(a11, b01, acc[(IH)*2+1][0]); \
  acc[(IH)*2+1][1] = MF32(a11, b11, acc[(IH)*2+1][1]); \
  __builtin_amdgcn_s_setprio(0); \
  VMX; \
  asm volatile("" ::: "memory"); \
  __builtin_amdgcn_s_barrier(); \
}

#define TILE32(B, I1, I2, I3, I4, VMX) { \
  bf16x8 b00, b01, b10, b11; \
  PH32((B) * 2 + 0, 0, 1, I1, (void)0) \
  PH32((B) * 2 + 0, 1, 0, I2, (void)0) \
  PH32((B) * 2 + 1, 0, 1, I3, (void)0) \
  PH32((B) * 2 + 1, 1, 0, I4, VMX) \
}

__global__ __launch_bounds__(512, 2) void gemm_fused8(
    const u16* __restrict__ Xb, const u16* __restrict__ Wb,
    const u16* __restrict__ Cb, const u16* __restrict__ Ub,
    float* __restrict__ out) {
  __shared__ __align__(16) u16 sm[65536];   // 128 KiB: A [0,32768), B [32768,65536)
  const int tid = threadIdx.x;
  const int bid = blockIdx.x;
  const int wg = (bid & 7) * 64 + (bid >> 3);   // XCD swizzle (nwg=512, 8|512)
  const int mt = wg >> 4;                        // 32 M-tiles
  const int nt = wg & 15;                        // 16 N-tiles
  const int m0 = mt * 256;
  const int n0 = nt * 256;
  const int lane = tid & 63;
  const int w = tid >> 6;
  const int wm = w >> 2;        // 0..1  (128 rows each)
  const int wn = w & 3;         // 0..3  (64 cols each)
  const int wmoff = wm * 4096;
  const int wnoff = wn * 2048;

  // 32x32 fragment lane constants
  const int row32 = lane & 31;
  const int kh = lane >> 5;
  const int rl = row32 >> 1;            // lrow within 32-row block
  const int xm = rl & 7;
  const int pb = (row32 & 1) * 4 + kh;  // c before ks and row-swizzle
  const int arl64 = rl * 64;
  const int cof0 = (pb ^ xm) * 8;            // ks=0 chunk offset (u16)
  const int cof1 = ((pb + 2) ^ xm) * 8;      // ks=1

  // staging map (unchanged): thread t stages chunks t and t+512 of a region
  const int c1 = (tid & 7) ^ ((tid >> 3) & 7);
  const int gr1 = 2 * (tid >> 3) + (c1 >> 2);
  const int kc1 = (c1 & 3) * 8;
  const u16* gA = Xb + (size_t)(m0 + gr1) * 4096 + kc1;
  const u16* gB = Wb + (size_t)(n0 + gr1) * 4096 + kc1;
  u16* dA = sm + tid * 8;
  u16* dB = sm + 32768 + tid * 8;

  f32x16 acc[4][2];
  #pragma unroll
  for (int i = 0; i < 4; ++i)
    #pragma unroll
    for (int j = 0; j < 2; ++j)
      #pragma unroll
      for (int r = 0; r < 16; ++r) acc[i][j][r] = 0.f;

  // prologue: tile0 (regs 0,1), tile1 h0 (reg 2). vmcnt(4) leaves reg2 in flight.
  STA(0, 0)  STB(0, 0)
  STA(1, 32) STB(1, 32)
  STA(2, 64) STB(2, 64)
  VM4;
  asm volatile("" ::: "memory");
  __builtin_amdgcn_s_barrier();

  for (int T = 0; T < 62; T += 2) {
    TILE32(0, STA(3, T * 64 + 96),  STB(3, T * 64 + 96),
              STA(0, T * 64 + 128), STB(0, T * 64 + 128), VM4)
    TILE32(1, STA(1, T * 64 + 160), STB(1, T * 64 + 160),
              STA(2, T * 64 + 192), STB(2, T * 64 + 192), VM4)
  }
  TILE32(0, STA(3, 4064), STB(3, 4064), (void)0, (void)0, VM0)
  TILE32(1, STC, STU, (void)0, (void)0, VM0)

  // LoRA K=32 tail from regions A0/B0 (same packed layout)
  {
    const u16* ap = sm + wmoff + arl64;
    const u16* bp = sm + 32768 + wnoff + arl64;
    bf16x8 b00 = *(const bf16x8*)(bp + cof0);
    bf16x8 b01 = *(const bf16x8*)(bp + cof1);
    bf16x8 b10 = *(const bf16x8*)(bp + 1024 + cof0);
    bf16x8 b11 = *(const bf16x8*)(bp + 1024 + cof1);
    #pragma unroll
    for (int mi = 0; mi < 4; ++mi) {
      bf16x8 a0 = *(const bf16x8*)(ap + mi * 1024 + cof0);
      bf16x8 a1 = *(const bf16x8*)(ap + mi * 1024 + cof1);
      acc[mi][0] = MF32(a0, b00, acc[mi][0]);
      acc[mi][1] = MF32(a0, b10, acc[mi][1]);
      acc[mi][0] = MF32(a1, b01, acc[mi][0]);
      acc[mi][1] = MF32(a1, b11, acc[mi][1]);
    }
  }

  // epilogue: 32x32 C/D layout: col=lane&31, row=(reg&3)+8*(reg>>2)+4*(lane>>5)
  const int colb = n0 + wn * 64 + row32;
  const int rbase = m0 + wm * 128 + 4 * kh;
  #pragma unroll
  for (int ti = 0; ti < 4; ++ti)
    #pragma unroll
    for (int j = 0; j < 2; ++j)
      #pragma unroll
      for (int r = 0; r < 16; ++r) {
        const int orow = rbase + ti * 32 + (r & 3) + 8 * (r >> 2);
        out[(size_t)orow * DOUT + colb + j * 32] = acc[ti][j][r];
      }
}

// ---------------------------------------------------------------------------
extern "C" void kernel_launch(void* const* d_in, const int* in_sizes, int n_in,
                              void* d_out, int out_size, void* d_ws, size_t ws_size,
                              hipStream_t stream) {
  const float* x     = (const float*)d_in[0];  // [4,2048,4096]
  const float* W     = (const float*)d_in[1];  // [4096,4096]
  const float* down  = (const float*)d_in[2];  // [5,4096,8]
  const float* up    = (const float*)d_in[3];  // [5,8,4096]
  const float* route = (const float*)d_in[4];  // [5,4096,5]
  float* out = (float*)d_out;

  char* ws = (char*)d_ws;
  u16*   Xb = (u16*)ws;                        // 64 MiB
  u16*   Wb = (u16*)(ws + 67108864);           // 32 MiB
  u16*   Cb = (u16*)(ws + 100663296);          // 512 KiB
  u16*   Ub = (u16*)(ws + 101187584);          // 256 KiB
  u16*   Wt = (u16*)(ws + 101449728);          // 384 KiB
  float* Pw = (float*)(ws + 101842944);        // 12 MiB

  prep_all<<<2048, 256, 0, stream>>>(x, W, up, route, down, Xb, Wb, Ub, Wt);
  coeffgemm<<<dim3(128, 8), 256, 0, stream>>>(Xb, Wt, Pw);
  reduce_coeff<<<128, 256, 0, stream>>>(Pw, Cb);
  gemm_fused8<<<512, 512, 0, stream>>>(Xb, Wb, Cb, Ub, out);
}

// Round 4
// 553.897 us; speedup vs baseline: 1.0440x; 1.0440x over previous
//
#include <hip/hip_runtime.h>
#include <hip/hip_bf16.h>

typedef unsigned short u16;
typedef __attribute__((ext_vector_type(8))) __bf16 bf16x8;
typedef __attribute__((ext_vector_type(4))) float f32x4;

#define DIN 4096
#define DOUT 4096
#define MROWS 8192

__device__ __forceinline__ u16 f2bf(float f) {
  unsigned int u = __float_as_uint(f);
  u += 0x7fffu + ((u >> 16) & 1u);   // RNE; inputs are finite randoms
  return (u16)(u >> 16);
}

__device__ __forceinline__ void gl2lds16(const void* g, void* l) {
  __builtin_amdgcn_global_load_lds(
      (const __attribute__((address_space(1))) unsigned int*)g,
      (__attribute__((address_space(3))) unsigned int*)l, 16, 0, 0);
}

// ---------------------------------------------------------------------------
// Kernel 1: fused prep (grid-stride casts + Ub transpose + Wt pack).
__global__ __launch_bounds__(256) void prep_all(
    const float* __restrict__ x, const float* __restrict__ W,
    const float* __restrict__ up, const float* __restrict__ route,
    const float* __restrict__ down,
    u16* __restrict__ Xb, u16* __restrict__ Wb,
    u16* __restrict__ Ub, u16* __restrict__ Wt) {
  const size_t NT = 2048 * 256;
  const size_t gtid = (size_t)blockIdx.x * 256 + threadIdx.x;

  if (gtid < 4096) {
    const int n = (int)gtid;
    union { u16 us[32]; uint4 q[4]; } o;
    #pragma unroll
    for (int c = 0; c < 32; ++c) o.us[c] = f2bf(up[(size_t)c * DOUT + n]);
    uint4* dst = (uint4*)(Ub + (size_t)n * 32);
    #pragma unroll
    for (int q = 0; q < 4; ++q) dst[q] = o.q[q];
  }

  if (gtid < 49152) {
    const int c = (int)(gtid >> 10);
    const int k0 = ((int)gtid & 1023) * 4;
    const float* route3 = route + 3 * DIN * 5;  // lora_route[3]
    float v[4];
    #pragma unroll
    for (int j = 0; j < 4; ++j) {
      int k = k0 + j;
      float f;
      if (c < 3)       f = route3[(size_t)k * 5 + c];
      else if (c < 35) f = down[(size_t)((c - 3) >> 3) * DIN * 8 + (size_t)k * 8 + ((c - 3) & 7)];
      else             f = 0.f;
      v[j] = f;
    }
    ushort4 o;
    o.x = f2bf(v[0]); o.y = f2bf(v[1]); o.z = f2bf(v[2]); o.w = f2bf(v[3]);
    *(ushort4*)(Wt + (size_t)c * DIN + k0) = o;
  }

  #pragma unroll 4
  for (int it = 0; it < 16; ++it) {
    size_t i = gtid + (size_t)it * NT;
    float4 v = ((const float4*)x)[i];
    ushort4 o;
    o.x = f2bf(v.x); o.y = f2bf(v.y); o.z = f2bf(v.z); o.w = f2bf(v.w);
    ((ushort4*)Xb)[i] = o;
  }

  #pragma unroll 4
  for (int it = 0; it < 8; ++it) {
    size_t i = gtid + (size_t)it * NT;
    float4 v = ((const float4*)W)[i];
    ushort4 o;
    o.x = f2bf(v.x); o.y = f2bf(v.y); o.z = f2bf(v.z); o.w = f2bf(v.w);
    ((ushort4*)Wb)[i] = o;
  }
}

// ---------------------------------------------------------------------------
// Kernel 2: coeff_full — replaces coeffgemm + reduce_coeff (no Pw roundtrip).
// 256 blocks x 32 rows, full K=4096 per block. Per super-iter: stage 4 K-tiles
// (wave w computes tile w only; K stride-4 interleave per wave), then
// cross-wave LDS reduce, per-row softmax on cols 0..2, gate, emit Cb bf16.
__global__ __launch_bounds__(256) void coeff_full(
    const u16* __restrict__ Xb, const u16* __restrict__ Wt,
    u16* __restrict__ Cb) {
  __shared__ __align__(16) u16 lds[20480];   // 40 KiB
  u16* As = lds;                 // 4 tiles x 32x64 u16 (2048 each)  [0,8192)
  u16* Bs = lds + 8192;          // 4 tiles x 48x64 u16 (3072 each)  [8192,20480)
  const int tid = threadIdx.x;
  const int m0 = blockIdx.x * 32;
  const int lane = tid & 63;
  const int w = tid >> 6;
  const int fm = lane & 15;
  const int xr = fm & 7;
  const int qd = lane >> 4;

  f32x4 acc[2][3];
  #pragma unroll
  for (int i = 0; i < 2; ++i)
    #pragma unroll
    for (int j = 0; j < 3; ++j) acc[i][j] = (f32x4){0.f, 0.f, 0.f, 0.f};

  // staging map: chunk L -> row=L>>3, c'=L&7, source col chunk c = c'^(row&7)
  const int arow = tid >> 3;                        // 0..31
  const int ac = ((tid & 7) ^ (arow & 7)) * 8;
  const u16* gA = Xb + (size_t)(m0 + arow) * DIN + ac;
  const u16* gBt = Wt + (size_t)arow * DIN + ac;    // rows 32..47 via +32*DIN (32%8==0)

  for (int s = 0; s < 16; ++s) {
    const int kb = s * 256;
    #pragma unroll
    for (int u = 0; u < 4; ++u) {
      gl2lds16(gA + kb + u * 64, As + u * 2048 + tid * 8);
      gl2lds16(gBt + kb + u * 64, Bs + u * 3072 + tid * 8);
      if (tid < 128)
        gl2lds16(gBt + 32 * DIN + kb + u * 64, Bs + u * 3072 + (256 + tid) * 8);
    }
    __syncthreads();
    const u16* Aw = As + w * 2048;
    const u16* Bw = Bs + w * 3072;
    #pragma unroll
    for (int kk = 0; kk < 64; kk += 32) {
      const int q = (kk >> 3) + qd;
      const int co = (q ^ xr) << 3;
      bf16x8 af[2], bfr[3];
      #pragma unroll
      for (int mi = 0; mi < 2; ++mi)
        af[mi] = *(const bf16x8*)(Aw + (mi * 16 + fm) * 64 + co);
      #pragma unroll
      for (int j = 0; j < 3; ++j)
        bfr[j] = *(const bf16x8*)(Bw + (j * 16 + fm) * 64 + co);
      #pragma unroll
      for (int mi = 0; mi < 2; ++mi)
        #pragma unroll
        for (int j = 0; j < 3; ++j)
          acc[mi][j] = __builtin_amdgcn_mfma_f32_16x16x32_bf16(af[mi], bfr[j], acc[mi][j], 0, 0, 0);
    }
    __syncthreads();
  }

  // cross-wave reduce: partials Pf[w][32][48] f32 reuse LDS (24 KiB)
  float* Pf = (float*)lds;
  const int em = qd * 4;
  const int en = fm;
  #pragma unroll
  for (int mi = 0; mi < 2; ++mi)
    #pragma unroll
    for (int j = 0; j < 3; ++j)
      #pragma unroll
      for (int r = 0; r < 4; ++r)
        Pf[(size_t)(w * 32 + mi * 16 + em + r) * 48 + j * 16 + en] = acc[mi][j][r];
  __syncthreads();

  float* Sf = (float*)(lds + 12288);   // 32x48 f32 at byte 24576
  {
    const int row = tid >> 3;
    const int cb = (tid & 7) * 6;
    #pragma unroll
    for (int c = 0; c < 6; ++c) {
      const int col = cb + c;
      float v = Pf[(size_t)(0 * 32 + row) * 48 + col]
              + Pf[(size_t)(1 * 32 + row) * 48 + col]
              + Pf[(size_t)(2 * 32 + row) * 48 + col]
              + Pf[(size_t)(3 * 32 + row) * 48 + col];
      Sf[row * 48 + col] = v;
    }
  }
  __syncthreads();

  float* om = (float*)(lds + 15360);   // 32x3 f32 at byte 30720
  if (tid < 32) {
    const float L0 = Sf[tid * 48 + 0], L1 = Sf[tid * 48 + 1], L2 = Sf[tid * 48 + 2];
    const float mx = fmaxf(L0, fmaxf(L1, L2));
    const float e0 = __expf(L0 - mx), e1 = __expf(L1 - mx), e2 = __expf(L2 - mx);
    const float inv = 1.f / (e0 + e1 + e2);
    om[tid * 3 + 0] = e0 * inv; om[tid * 3 + 1] = e1 * inv; om[tid * 3 + 2] = e2 * inv;
  }
  __syncthreads();

  {
    const int row = tid >> 3;
    const int c4 = (tid & 7) * 4;
    u16 tmp[4];
    #pragma unroll
    for (int c = 0; c < 4; ++c) {
      const int oc = c4 + c;            // output col 0..31
      const int ex = oc >> 3;           // expert bucket
      const float wgt = (ex < 3) ? om[row * 3 + ex] : 1.f;
      tmp[c] = f2bf(Sf[row * 48 + 3 + oc] * wgt);
    }
    ushort4 o; o.x = tmp[0]; o.y = tmp[1]; o.z = tmp[2]; o.w = tmp[3];
    *(ushort4*)(Cb + (size_t)(m0 + row) * 32 + c4) = o;
  }
}

// ---------------------------------------------------------------------------
// Kernel 3: out = Xb @ Wb^T + Cb @ Ub^T.  REVERTED to the round-1 16x16
// version (measured 232.9 us, 0 bank conflicts). NOTE: the 32x32x16 port
// (round 3) triggered 25.4M conflict-cycles/dispatch in this packed layout
// and lost 13% — keep 16x16x32 here.

#define MF(a, b, c) __builtin_amdgcn_mfma_f32_16x16x32_bf16(a, b, c, 0, 0, 0)

#define MROW(A, I) \
  acc[I][0] = MF(A, bfr0, acc[I][0]); \
  acc[I][1] = MF(A, bfr1, acc[I][1]); \
  acc[I][2] = MF(A, bfr2, acc[I][2]); \
  acc[I][3] = MF(A, bfr3, acc[I][3]);

#define VM4 asm volatile("s_waitcnt vmcnt(4)" ::: "memory")
#define VM0 asm volatile("s_waitcnt vmcnt(0)" ::: "memory")

#define STA(REG, KOFF) { const u16* s_ = gA + (KOFF); \
  gl2lds16(s_, dA + (REG) * 8192); \
  gl2lds16(s_ + 128 * 4096, dA + (REG) * 8192 + 4096); }
#define STB(REG, KOFF) { const u16* s_ = gB + (KOFF); \
  gl2lds16(s_, dB + (REG) * 8192); \
  gl2lds16(s_ + 128 * 4096, dB + (REG) * 8192 + 4096); }
#define STC { const u16* s_ = Cb + (size_t)(m0 + gr1) * 32 + kc1; \
  gl2lds16(s_, dA); gl2lds16(s_ + 128 * 32, dA + 4096); }
#define STU { const u16* s_ = Ub + (size_t)(n0 + gr1) * 32 + kc1; \
  gl2lds16(s_, dB); gl2lds16(s_ + 128 * 32, dB + 4096); }

#define PH(REG, IH, LOADB, ISSUE, VMX) { \
  const u16* ap_ = sm + (REG) * 8192 + wmoff + (IH) * 2048 + off0; \
  bf16x8 af0 = *(const bf16x8*)(ap_); \
  bf16x8 af1 = *(const bf16x8*)(ap_ + 512); \
  bf16x8 af2 = *(const bf16x8*)(ap_ + 1024); \
  bf16x8 af3 = *(const bf16x8*)(ap_ + 1536); \
  if (LOADB) { \
    const u16* bp_ = sm + 32768 + (REG) * 8192 + wnoff + off0; \
    bfr0 = *(const bf16x8*)(bp_); \
    bfr1 = *(const bf16x8*)(bp_ + 512); \
    bfr2 = *(const bf16x8*)(bp_ + 1024); \
    bfr3 = *(const bf16x8*)(bp_ + 1536); \
  } \
  ISSUE; \
  asm volatile("" ::: "memory"); \
  __builtin_amdgcn_s_barrier(); \
  __builtin_amdgcn_s_setprio(1); \
  MROW(af0, (IH) * 4 + 0) \
  MROW(af1, (IH) * 4 + 1) \
  MROW(af2, (IH) * 4 + 2) \
  MROW(af3, (IH) * 4 + 3) \
  __builtin_amdgcn_s_setprio(0); \
  VMX; \
  asm volatile("" ::: "memory"); \
  __builtin_amdgcn_s_barrier(); \
}

#define TILE(B, I1, I2, I3, I4, VMX) { \
  bf16x8 bfr0, bfr1, bfr2, bfr3; \
  PH((B) * 2 + 0, 0, 1, I1, (void)0) \
  PH((B) * 2 + 0, 1, 0, I2, (void)0) \
  PH((B) * 2 + 1, 0, 1, I3, (void)0) \
  PH((B) * 2 + 1, 1, 0, I4, VMX) \
}

__global__ __launch_bounds__(512, 2) void gemm_fused8(
    const u16* __restrict__ Xb, const u16* __restrict__ Wb,
    const u16* __restrict__ Cb, const u16* __restrict__ Ub,
    float* __restrict__ out) {
  __shared__ __align__(16) u16 sm[65536];   // 128 KiB: A [0,32768), B [32768,65536)
  const int tid = threadIdx.x;
  const int bid = blockIdx.x;
  const int wg = (bid & 7) * 64 + (bid >> 3);   // XCD swizzle (nwg=512, 8|512)
  const int mt = wg >> 4;                        // 32 M-tiles
  const int nt = wg & 15;                        // 16 N-tiles
  const int m0 = mt * 256;
  const int n0 = nt * 256;
  const int lane = tid & 63;
  const int w = tid >> 6;
  const int wm = w >> 2;        // 0..1  (128 rows each)
  const int wn = w & 3;         // 0..3  (64 cols each)
  const int fm = lane & 15;
  const int qd = lane >> 4;
  const int off0 = (fm >> 1) * 64 + (((((fm & 1) << 2) | qd)) ^ (fm >> 1)) * 8;
  const int wmoff = wm * 4096;
  const int wnoff = wn * 2048;

  const int c1 = (tid & 7) ^ ((tid >> 3) & 7);
  const int gr1 = 2 * (tid >> 3) + (c1 >> 2);
  const int kc1 = (c1 & 3) * 8;
  const u16* gA = Xb + (size_t)(m0 + gr1) * 4096 + kc1;
  const u16* gB = Wb + (size_t)(n0 + gr1) * 4096 + kc1;
  u16* dA = sm + tid * 8;
  u16* dB = sm + 32768 + tid * 8;

  f32x4 acc[8][4];
  #pragma unroll
  for (int i = 0; i < 8; ++i)
    #pragma unroll
    for (int j = 0; j < 4; ++j) acc[i][j] = (f32x4){0.f, 0.f, 0.f, 0.f};

  STA(0, 0)  STB(0, 0)
  STA(1, 32) STB(1, 32)
  STA(2, 64) STB(2, 64)
  VM4;
  asm volatile("" ::: "memory");
  __builtin_amdgcn_s_barrier();

  for (int T = 0; T < 62; T += 2) {
    TILE(0, STA(3, T * 64 + 96),  STB(3, T * 64 + 96),
            STA(0, T * 64 + 128), STB(0, T * 64 + 128), VM4)
    TILE(1, STA(1, T * 64 + 160), STB(1, T * 64 + 160),
            STA(2, T * 64 + 192), STB(2, T * 64 + 192), VM4)
  }
  TILE(0, STA(3, 4064), STB(3, 4064), (void)0, (void)0, VM0)
  TILE(1, STC, STU, (void)0, (void)0, VM0)

  // LoRA K=32 tail from regions A0/B0
  {
    const u16* ap = sm + wmoff + off0;
    const u16* bp = sm + 32768 + wnoff + off0;
    bf16x8 bfr0 = *(const bf16x8*)(bp);
    bf16x8 bfr1 = *(const bf16x8*)(bp + 512);
    bf16x8 bfr2 = *(const bf16x8*)(bp + 1024);
    bf16x8 bfr3 = *(const bf16x8*)(bp + 1536);
    #pragma unroll
    for (int i = 0; i < 8; ++i) {
      bf16x8 a = *(const bf16x8*)(ap + i * 512);
      acc[i][0] = MF(a, bfr0, acc[i][0]);
      acc[i][1] = MF(a, bfr1, acc[i][1]);
      acc[i][2] = MF(a, bfr2, acc[i][2]);
      acc[i][3] = MF(a, bfr3, acc[i][3]);
    }
  }

  const int em = qd * 4;
  const int en = fm;
  const size_t obase = (size_t)(m0 + wm * 128) * DOUT + n0 + wn * 64 + en;
  #pragma unroll
  for (int i = 0; i < 8; ++i)
    #pragma unroll
    for (int j = 0; j < 4; ++j)
      #pragma unroll
      for (int r = 0; r < 4; ++r)
        out[obase + (size_t)(i * 16 + em + r) * DOUT + j * 16] = acc[i][j][r];
}

// ---------------------------------------------------------------------------
extern "C" void kernel_launch(void* const* d_in, const int* in_sizes, int n_in,
                              void* d_out, int out_size, void* d_ws, size_t ws_size,
                              hipStream_t stream) {
  const float* x     = (const float*)d_in[0];  // [4,2048,4096]
  const float* W     = (const float*)d_in[1];  // [4096,4096]
  const float* down  = (const float*)d_in[2];  // [5,4096,8]
  const float* up    = (const float*)d_in[3];  // [5,8,4096]
  const float* route = (const float*)d_in[4];  // [5,4096,5]
  float* out = (float*)d_out;

  char* ws = (char*)d_ws;
  u16*   Xb = (u16*)ws;                        // 64 MiB
  u16*   Wb = (u16*)(ws + 67108864);           // 32 MiB
  u16*   Cb = (u16*)(ws + 100663296);          // 512 KiB
  u16*   Ub = (u16*)(ws + 101187584);          // 256 KiB
  u16*   Wt = (u16*)(ws + 101449728);          // 384 KiB

  prep_all<<<2048, 256, 0, stream>>>(x, W, up, route, down, Xb, Wb, Ub, Wt);
  coeff_full<<<256, 256, 0, stream>>>(Xb, Wt, Cb);
  gemm_fused8<<<512, 512, 0, stream>>>(Xb, Wb, Cb, Ub, out);
}

// Round 5
// 512.679 us; speedup vs baseline: 1.1279x; 1.0804x over previous
//
#include <hip/hip_runtime.h>
#include <hip/hip_bf16.h>

typedef unsigned short u16;
typedef __attribute__((ext_vector_type(8))) __bf16 bf16x8;
typedef __attribute__((ext_vector_type(4))) float f32x4;

#define DIN 4096
#define DOUT 4096
#define MROWS 8192

__device__ __forceinline__ u16 f2bf(float f) {
  unsigned int u = __float_as_uint(f);
  u += 0x7fffu + ((u >> 16) & 1u);   // RNE; inputs are finite randoms
  return (u16)(u >> 16);
}

__device__ __forceinline__ void gl2lds16(const void* g, void* l) {
  __builtin_amdgcn_global_load_lds(
      (const __attribute__((address_space(1))) unsigned int*)g,
      (__attribute__((address_space(3))) unsigned int*)l, 16, 0, 0);
}

// ---------------------------------------------------------------------------
// Prep kernels: RESTORED to round-1 config (separate kernels measured faster
// than fused prep_all: R1 521.7 vs R2 533.0 vs R4 553.9; fusion refuted).

// Kernel 0: x fp32 -> bf16
__global__ __launch_bounds__(256) void convx(const float* __restrict__ x,
                                             u16* __restrict__ Xb) {
  size_t i = ((size_t)blockIdx.x * 256 + threadIdx.x) * 4;
  float4 v = *(const float4*)(x + i);
  ushort4 o;
  o.x = f2bf(v.x); o.y = f2bf(v.y); o.z = f2bf(v.z); o.w = f2bf(v.w);
  *(ushort4*)(Xb + i) = o;
}

// Kernel 1: W fp32 -> bf16 (B^T layout is W's native [DOUT][DIN] layout)
__global__ __launch_bounds__(256) void convw(const float* __restrict__ W,
                                             u16* __restrict__ Wb) {
  size_t i = ((size_t)blockIdx.x * 256 + threadIdx.x) * 4;
  float4 v = *(const float4*)(W + i);
  ushort4 o;
  o.x = f2bf(v.x); o.y = f2bf(v.y); o.z = f2bf(v.z); o.w = f2bf(v.w);
  *(ushort4*)(Wb + i) = o;
}

// Kernel 2: Ub[n][c] = bf16(lora_up_flat[c][n]), c<32 (transpose)
__global__ __launch_bounds__(256) void convu(const float* __restrict__ up,
                                             u16* __restrict__ Ub) {
  int n = blockIdx.x * 256 + threadIdx.x;
  union { u16 us[32]; uint4 q[4]; } o;
  #pragma unroll
  for (int c = 0; c < 32; ++c) o.us[c] = f2bf(up[(size_t)c * DOUT + n]);
  uint4* dst = (uint4*)(Ub + (size_t)n * 32);
  #pragma unroll
  for (int q = 0; q < 4; ++q) dst[q] = o.q[q];
}

// Kernel 3a: pack coeff-GEMM weights Wt[48][4096] bf16.
__global__ __launch_bounds__(256) void wtprep(const float* __restrict__ route,
                                              const float* __restrict__ down,
                                              u16* __restrict__ Wt) {
  const int c = blockIdx.y;
  const int k0 = blockIdx.x * 1024 + threadIdx.x * 4;
  const float* route3 = route + 3 * DIN * 5;  // lora_route[3]
  float v[4];
  #pragma unroll
  for (int j = 0; j < 4; ++j) {
    int k = k0 + j;
    float f;
    if (c < 3)       f = route3[(size_t)k * 5 + c];
    else if (c < 35) f = down[(size_t)((c - 3) >> 3) * DIN * 8 + (size_t)k * 8 + ((c - 3) & 7)];
    else             f = 0.f;
    v[j] = f;
  }
  ushort4 o;
  o.x = f2bf(v[0]); o.y = f2bf(v[1]); o.z = f2bf(v[2]); o.w = f2bf(v[3]);
  *(ushort4*)(Wt + (size_t)c * DIN + k0) = o;
}

// Kernel 3b: MFMA tall-skinny GEMM Pw[split][8192][48] = Xb . Wt^T (R1 version).
__global__ __launch_bounds__(256) void coeffgemm(
    const u16* __restrict__ Xb, const u16* __restrict__ Wt,
    float* __restrict__ Pw) {
  __shared__ __align__(16) u16 As[128 * 64];
  __shared__ __align__(16) u16 Bs[48 * 64];
  const int tid = threadIdx.x;
  const int m0 = blockIdx.x * 128;
  const int kb = blockIdx.y * 512;
  const int lane = tid & 63;
  const int w = tid >> 6;
  const int wr = w * 32;
  const int fm = lane & 15;
  const int xr = fm & 7;
  const int qd = lane >> 4;

  f32x4 acc[2][3];
  #pragma unroll
  for (int i = 0; i < 2; ++i)
    #pragma unroll
    for (int j = 0; j < 3; ++j) acc[i][j] = (f32x4){0.f, 0.f, 0.f, 0.f};

  const int srow = tid >> 3;                        // 0..31
  const int scol = ((tid & 7) ^ (srow & 7)) * 8;    // swizzled source chunk
  const u16* gA = Xb + (size_t)(m0 + srow) * DIN + kb + scol;
  u16* lA = As + tid * 8;

  for (int kc = 0; kc < 512; kc += 64) {
    gl2lds16(Wt + (size_t)srow * DIN + kb + kc + scol, Bs + tid * 8);
    if (tid < 128) {
      int u = 256 + tid;
      int usw = ((u & 7) ^ ((u >> 3) & 7)) * 8;
      gl2lds16(Wt + (size_t)(u >> 3) * DIN + kb + kc + usw, Bs + u * 8);
    }
    #pragma unroll
    for (int it = 0; it < 4; ++it)
      gl2lds16(gA + kc + (size_t)(it * 32) * DIN, lA + it * 2048);
    __syncthreads();
    #pragma unroll
    for (int kk = 0; kk < 64; kk += 32) {
      const int q = (kk >> 3) + qd;
      bf16x8 af[2], bfr[3];
      #pragma unroll
      for (int i = 0; i < 2; ++i)
        af[i] = *(const bf16x8*)(As + (wr + i * 16 + fm) * 64 + ((q ^ xr) << 3));
      #pragma unroll
      for (int j = 0; j < 3; ++j)
        bfr[j] = *(const bf16x8*)(Bs + (j * 16 + fm) * 64 + ((q ^ xr) << 3));
      #pragma unroll
      for (int i = 0; i < 2; ++i)
        #pragma unroll
        for (int j = 0; j < 3; ++j)
          acc[i][j] = __builtin_amdgcn_mfma_f32_16x16x32_bf16(af[i], bfr[j], acc[i][j], 0, 0, 0);
    }
    __syncthreads();
  }
  const int em = (lane >> 4) * 4;
  const int en = lane & 15;
  const size_t pbase = (size_t)blockIdx.y * MROWS;
  #pragma unroll
  for (int i = 0; i < 2; ++i)
    #pragma unroll
    for (int j = 0; j < 3; ++j)
      #pragma unroll
      for (int r = 0; r < 4; ++r)
        Pw[(pbase + m0 + wr + i * 16 + em + r) * 48 + j * 16 + en] = acc[i][j][r];
}

// Kernel 3c: reduce 8 K-split partials + softmax gate -> Cb bf16 (128 blocks,
// coalesced; bit-identical per-column sp-order).
__global__ __launch_bounds__(256) void reduce_coeff(const float* __restrict__ Pw,
                                                    u16* __restrict__ Cb) {
  const int tid = threadIdx.x;
  const int rl = tid >> 2;
  const int cg = tid & 3;
  const int m = blockIdx.x * 64 + rl;
  const int lane = tid & 63;

  float s[12];
  #pragma unroll
  for (int q = 0; q < 12; ++q) s[q] = 0.f;
  for (int sp = 0; sp < 8; ++sp) {
    const float4* p = (const float4*)(Pw + ((size_t)sp * MROWS + m) * 48 + cg * 12);
    #pragma unroll
    for (int q = 0; q < 3; ++q) {
      float4 v = p[q];
      s[q * 4 + 0] += v.x; s[q * 4 + 1] += v.y;
      s[q * 4 + 2] += v.z; s[q * 4 + 3] += v.w;
    }
  }
  const int src = lane & ~3;
  const float L0 = __shfl(s[0], src);
  const float L1 = __shfl(s[1], src);
  const float L2 = __shfl(s[2], src);
  const float mx = fmaxf(L0, fmaxf(L1, L2));
  const float e0 = __expf(L0 - mx), e1 = __expf(L1 - mx), e2 = __expf(L2 - mx);
  const float inv = 1.f / (e0 + e1 + e2);
  const float om0 = e0 * inv, om1 = e1 * inv, om2 = e2 * inv;
  #pragma unroll
  for (int j = 0; j < 12; ++j) {
    const int G = cg * 12 + j;
    if (G >= 3 && G < 35) {
      const float wgt = (G < 11) ? om0 : (G < 19) ? om1 : (G < 27) ? om2 : 1.f;
      Cb[(size_t)m * 32 + (G - 3)] = f2bf(s[j] * wgt);
    }
  }
}

// ---------------------------------------------------------------------------
// Kernel 4: out = Xb @ Wb^T + Cb @ Ub^T.
// EXPERIMENT: phase merge 4->2 per K-tile. Each merged phase = {read 8 A-frags
// + 4 B-frags of one K=32 region | issue 4 gl2lds | barrier | setprio(1)
// 32xMFMA setprio(0) | [vmcnt] | barrier}. Halves barriers/K-tile (8->4),
// doubles MFMA cluster (16->32) to amortize post-barrier lgkm stall.
// Region-liveness ledger, ds_read count, swizzle, vmcnt(4)-per-tile drain,
// and per-acc K-order all IDENTICAL to the round-1 kernel (bit-identical out).

#define MF(a, b, c) __builtin_amdgcn_mfma_f32_16x16x32_bf16(a, b, c, 0, 0, 0)

#define MROW(A, I) \
  acc[I][0] = MF(A, bfr0, acc[I][0]); \
  acc[I][1] = MF(A, bfr1, acc[I][1]); \
  acc[I][2] = MF(A, bfr2, acc[I][2]); \
  acc[I][3] = MF(A, bfr3, acc[I][3]);

#define VM4 asm volatile("s_waitcnt vmcnt(4)" ::: "memory")
#define VM0 asm volatile("s_waitcnt vmcnt(0)" ::: "memory")

#define STA(REG, KOFF) { const u16* s_ = gA + (KOFF); \
  gl2lds16(s_, dA + (REG) * 8192); \
  gl2lds16(s_ + 128 * 4096, dA + (REG) * 8192 + 4096); }
#define STB(REG, KOFF) { const u16* s_ = gB + (KOFF); \
  gl2lds16(s_, dB + (REG) * 8192); \
  gl2lds16(s_ + 128 * 4096, dB + (REG) * 8192 + 4096); }
#define STAB(REG, KOFF) { STA(REG, KOFF) STB(REG, KOFF) }
#define STC { const u16* s_ = Cb + (size_t)(m0 + gr1) * 32 + kc1; \
  gl2lds16(s_, dA); gl2lds16(s_ + 128 * 32, dA + 4096); }
#define STU { const u16* s_ = Ub + (size_t)(n0 + gr1) * 32 + kc1; \
  gl2lds16(s_, dB); gl2lds16(s_ + 128 * 32, dB + 4096); }
#define STCU { STC STU }

#define PH2(REG, ISSUE, VMX) { \
  const u16* ap_ = sm + (REG) * 8192 + wmoff + off0; \
  bf16x8 af0 = *(const bf16x8*)(ap_); \
  bf16x8 af1 = *(const bf16x8*)(ap_ + 512); \
  bf16x8 af2 = *(const bf16x8*)(ap_ + 1024); \
  bf16x8 af3 = *(const bf16x8*)(ap_ + 1536); \
  bf16x8 af4 = *(const bf16x8*)(ap_ + 2048); \
  bf16x8 af5 = *(const bf16x8*)(ap_ + 2560); \
  bf16x8 af6 = *(const bf16x8*)(ap_ + 3072); \
  bf16x8 af7 = *(const bf16x8*)(ap_ + 3584); \
  const u16* bp_ = sm + 32768 + (REG) * 8192 + wnoff + off0; \
  bf16x8 bfr0 = *(const bf16x8*)(bp_); \
  bf16x8 bfr1 = *(const bf16x8*)(bp_ + 512); \
  bf16x8 bfr2 = *(const bf16x8*)(bp_ + 1024); \
  bf16x8 bfr3 = *(const bf16x8*)(bp_ + 1536); \
  ISSUE; \
  asm volatile("" ::: "memory"); \
  __builtin_amdgcn_s_barrier(); \
  __builtin_amdgcn_s_setprio(1); \
  MROW(af0, 0) MROW(af1, 1) MROW(af2, 2) MROW(af3, 3) \
  MROW(af4, 4) MROW(af5, 5) MROW(af6, 6) MROW(af7, 7) \
  __builtin_amdgcn_s_setprio(0); \
  VMX; \
  asm volatile("" ::: "memory"); \
  __builtin_amdgcn_s_barrier(); \
}

#define TILE2(B, I1, I2, VMX) { \
  PH2((B) * 2 + 0, I1, (void)0) \
  PH2((B) * 2 + 1, I2, VMX) \
}

__global__ __launch_bounds__(512, 2) void gemm_fused8(
    const u16* __restrict__ Xb, const u16* __restrict__ Wb,
    const u16* __restrict__ Cb, const u16* __restrict__ Ub,
    float* __restrict__ out) {
  __shared__ __align__(16) u16 sm[65536];   // 128 KiB: A [0,32768), B [32768,65536)
  const int tid = threadIdx.x;
  const int bid = blockIdx.x;
  const int wg = (bid & 7) * 64 + (bid >> 3);   // XCD swizzle (nwg=512, 8|512)
  const int mt = wg >> 4;                        // 32 M-tiles
  const int nt = wg & 15;                        // 16 N-tiles
  const int m0 = mt * 256;
  const int n0 = nt * 256;
  const int lane = tid & 63;
  const int w = tid >> 6;
  const int wm = w >> 2;        // 0..1  (128 rows each)
  const int wn = w & 3;         // 0..3  (64 cols each)
  const int fm = lane & 15;
  const int qd = lane >> 4;
  const int off0 = (fm >> 1) * 64 + (((((fm & 1) << 2) | qd)) ^ (fm >> 1)) * 8;
  const int wmoff = wm * 4096;
  const int wnoff = wn * 2048;

  const int c1 = (tid & 7) ^ ((tid >> 3) & 7);
  const int gr1 = 2 * (tid >> 3) + (c1 >> 2);
  const int kc1 = (c1 & 3) * 8;
  const u16* gA = Xb + (size_t)(m0 + gr1) * 4096 + kc1;
  const u16* gB = Wb + (size_t)(n0 + gr1) * 4096 + kc1;
  u16* dA = sm + tid * 8;
  u16* dB = sm + 32768 + tid * 8;

  f32x4 acc[8][4];
  #pragma unroll
  for (int i = 0; i < 8; ++i)
    #pragma unroll
    for (int j = 0; j < 4; ++j) acc[i][j] = (f32x4){0.f, 0.f, 0.f, 0.f};

  // prologue: tile0 (regs 0,1), tile1 h0 (reg 2). vmcnt(4) leaves reg2 in flight.
  STA(0, 0)  STB(0, 0)
  STA(1, 32) STB(1, 32)
  STA(2, 64) STB(2, 64)
  VM4;
  asm volatile("" ::: "memory");
  __builtin_amdgcn_s_barrier();

  // main loop: 2 tiles/iter; per tile mp1 issues (T+1)h1, mp2 issues (T+2)h0.
  for (int T = 0; T < 62; T += 2) {
    TILE2(0, STAB(3, T * 64 + 96),  STAB(0, T * 64 + 128), VM4)
    TILE2(1, STAB(1, T * 64 + 160), STAB(2, T * 64 + 192), VM4)
  }
  // tile 62: issue tile63 h1; drain.
  TILE2(0, STAB(3, 4064), (void)0, VM0)
  // tile 63: issue LoRA stages (Cb->A reg0, Ub->B reg0); drain.
  TILE2(1, STCU, (void)0, VM0)

  // LoRA K=32 tail from regions A0/B0
  {
    const u16* ap = sm + wmoff + off0;
    const u16* bp = sm + 32768 + wnoff + off0;
    bf16x8 bfr0 = *(const bf16x8*)(bp);
    bf16x8 bfr1 = *(const bf16x8*)(bp + 512);
    bf16x8 bfr2 = *(const bf16x8*)(bp + 1024);
    bf16x8 bfr3 = *(const bf16x8*)(bp + 1536);
    #pragma unroll
    for (int i = 0; i < 8; ++i) {
      bf16x8 a = *(const bf16x8*)(ap + i * 512);
      acc[i][0] = MF(a, bfr0, acc[i][0]);
      acc[i][1] = MF(a, bfr1, acc[i][1]);
      acc[i][2] = MF(a, bfr2, acc[i][2]);
      acc[i][3] = MF(a, bfr3, acc[i][3]);
    }
  }

  // epilogue: C/D layout col=lane&15, row=(lane>>4)*4+reg
  const int em = qd * 4;
  const int en = fm;
  const size_t obase = (size_t)(m0 + wm * 128) * DOUT + n0 + wn * 64 + en;
  #pragma unroll
  for (int i = 0; i < 8; ++i)
    #pragma unroll
    for (int j = 0; j < 4; ++j)
      #pragma unroll
      for (int r = 0; r < 4; ++r)
        out[obase + (size_t)(i * 16 + em + r) * DOUT + j * 16] = acc[i][j][r];
}

// ---------------------------------------------------------------------------
extern "C" void kernel_launch(void* const* d_in, const int* in_sizes, int n_in,
                              void* d_out, int out_size, void* d_ws, size_t ws_size,
                              hipStream_t stream) {
  const float* x     = (const float*)d_in[0];  // [4,2048,4096]
  const float* W     = (const float*)d_in[1];  // [4096,4096]
  const float* down  = (const float*)d_in[2];  // [5,4096,8]
  const float* up    = (const float*)d_in[3];  // [5,8,4096]
  const float* route = (const float*)d_in[4];  // [5,4096,5]
  float* out = (float*)d_out;

  char* ws = (char*)d_ws;
  u16*   Xb = (u16*)ws;                        // 64 MiB
  u16*   Wb = (u16*)(ws + 67108864);           // 32 MiB
  u16*   Cb = (u16*)(ws + 100663296);          // 512 KiB
  u16*   Ub = (u16*)(ws + 101187584);          // 256 KiB
  u16*   Wt = (u16*)(ws + 101449728);          // 384 KiB
  float* Pw = (float*)(ws + 101842944);        // 12 MiB

  convx<<<32768, 256, 0, stream>>>(x, Xb);
  convw<<<16384, 256, 0, stream>>>(W, Wb);
  convu<<<16, 256, 0, stream>>>(up, Ub);
  wtprep<<<dim3(4, 48), 256, 0, stream>>>(route, down, Wt);
  coeffgemm<<<dim3(64, 8), 256, 0, stream>>>(Xb, Wt, Pw);
  reduce_coeff<<<128, 256, 0, stream>>>(Pw, Cb);
  gemm_fused8<<<512, 512, 0, stream>>>(Xb, Wb, Cb, Ub, out);
}

// Round 6
// 510.226 us; speedup vs baseline: 1.1333x; 1.0048x over previous
//
#include <hip/hip_runtime.h>
#include <hip/hip_bf16.h>

typedef unsigned short u16;
typedef __attribute__((ext_vector_type(8))) __bf16 bf16x8;
typedef __attribute__((ext_vector_type(4))) float f32x4;

#define DIN 4096
#define DOUT 4096
#define MROWS 8192

__device__ __forceinline__ u16 f2bf(float f) {
  unsigned int u = __float_as_uint(f);
  u += 0x7fffu + ((u >> 16) & 1u);   // RNE; inputs are finite randoms
  return (u16)(u >> 16);
}

__device__ __forceinline__ void gl2lds16(const void* g, void* l) {
  __builtin_amdgcn_global_load_lds(
      (const __attribute__((address_space(1))) unsigned int*)g,
      (__attribute__((address_space(3))) unsigned int*)l, 16, 0, 0);
}

// ---------------------------------------------------------------------------
// Prep chain: best-measured configuration (round 5): separate cast kernels +
// R1 coeffgemm + 128-block coalesced reduce_coeff.  ~50 us total, ~2 us above
// its streaming arithmetic floor — prep is converged.

// Kernel 0: x fp32 -> bf16
__global__ __launch_bounds__(256) void convx(const float* __restrict__ x,
                                             u16* __restrict__ Xb) {
  size_t i = ((size_t)blockIdx.x * 256 + threadIdx.x) * 4;
  float4 v = *(const float4*)(x + i);
  ushort4 o;
  o.x = f2bf(v.x); o.y = f2bf(v.y); o.z = f2bf(v.z); o.w = f2bf(v.w);
  *(ushort4*)(Xb + i) = o;
}

// Kernel 1: W fp32 -> bf16 (B^T layout is W's native [DOUT][DIN] layout)
__global__ __launch_bounds__(256) void convw(const float* __restrict__ W,
                                             u16* __restrict__ Wb) {
  size_t i = ((size_t)blockIdx.x * 256 + threadIdx.x) * 4;
  float4 v = *(const float4*)(W + i);
  ushort4 o;
  o.x = f2bf(v.x); o.y = f2bf(v.y); o.z = f2bf(v.z); o.w = f2bf(v.w);
  *(ushort4*)(Wb + i) = o;
}

// Kernel 2: Ub[n][c] = bf16(lora_up_flat[c][n]), c<32 (transpose)
__global__ __launch_bounds__(256) void convu(const float* __restrict__ up,
                                             u16* __restrict__ Ub) {
  int n = blockIdx.x * 256 + threadIdx.x;
  union { u16 us[32]; uint4 q[4]; } o;
  #pragma unroll
  for (int c = 0; c < 32; ++c) o.us[c] = f2bf(up[(size_t)c * DOUT + n]);
  uint4* dst = (uint4*)(Ub + (size_t)n * 32);
  #pragma unroll
  for (int q = 0; q < 4; ++q) dst[q] = o.q[q];
}

// Kernel 3a: pack coeff-GEMM weights Wt[48][4096] bf16.
__global__ __launch_bounds__(256) void wtprep(const float* __restrict__ route,
                                              const float* __restrict__ down,
                                              u16* __restrict__ Wt) {
  const int c = blockIdx.y;
  const int k0 = blockIdx.x * 1024 + threadIdx.x * 4;
  const float* route3 = route + 3 * DIN * 5;  // lora_route[3]
  float v[4];
  #pragma unroll
  for (int j = 0; j < 4; ++j) {
    int k = k0 + j;
    float f;
    if (c < 3)       f = route3[(size_t)k * 5 + c];
    else if (c < 35) f = down[(size_t)((c - 3) >> 3) * DIN * 8 + (size_t)k * 8 + ((c - 3) & 7)];
    else             f = 0.f;
    v[j] = f;
  }
  ushort4 o;
  o.x = f2bf(v[0]); o.y = f2bf(v[1]); o.z = f2bf(v[2]); o.w = f2bf(v[3]);
  *(ushort4*)(Wt + (size_t)c * DIN + k0) = o;
}

// Kernel 3b: MFMA tall-skinny GEMM Pw[split][8192][48] = Xb . Wt^T.
__global__ __launch_bounds__(256) void coeffgemm(
    const u16* __restrict__ Xb, const u16* __restrict__ Wt,
    float* __restrict__ Pw) {
  __shared__ __align__(16) u16 As[128 * 64];
  __shared__ __align__(16) u16 Bs[48 * 64];
  const int tid = threadIdx.x;
  const int m0 = blockIdx.x * 128;
  const int kb = blockIdx.y * 512;
  const int lane = tid & 63;
  const int w = tid >> 6;
  const int wr = w * 32;
  const int fm = lane & 15;
  const int xr = fm & 7;
  const int qd = lane >> 4;

  f32x4 acc[2][3];
  #pragma unroll
  for (int i = 0; i < 2; ++i)
    #pragma unroll
    for (int j = 0; j < 3; ++j) acc[i][j] = (f32x4){0.f, 0.f, 0.f, 0.f};

  const int srow = tid >> 3;                        // 0..31
  const int scol = ((tid & 7) ^ (srow & 7)) * 8;    // swizzled source chunk
  const u16* gA = Xb + (size_t)(m0 + srow) * DIN + kb + scol;
  u16* lA = As + tid * 8;

  for (int kc = 0; kc < 512; kc += 64) {
    gl2lds16(Wt + (size_t)srow * DIN + kb + kc + scol, Bs + tid * 8);
    if (tid < 128) {
      int u = 256 + tid;
      int usw = ((u & 7) ^ ((u >> 3) & 7)) * 8;
      gl2lds16(Wt + (size_t)(u >> 3) * DIN + kb + kc + usw, Bs + u * 8);
    }
    #pragma unroll
    for (int it = 0; it < 4; ++it)
      gl2lds16(gA + kc + (size_t)(it * 32) * DIN, lA + it * 2048);
    __syncthreads();
    #pragma unroll
    for (int kk = 0; kk < 64; kk += 32) {
      const int q = (kk >> 3) + qd;
      bf16x8 af[2], bfr[3];
      #pragma unroll
      for (int i = 0; i < 2; ++i)
        af[i] = *(const bf16x8*)(As + (wr + i * 16 + fm) * 64 + ((q ^ xr) << 3));
      #pragma unroll
      for (int j = 0; j < 3; ++j)
        bfr[j] = *(const bf16x8*)(Bs + (j * 16 + fm) * 64 + ((q ^ xr) << 3));
      #pragma unroll
      for (int i = 0; i < 2; ++i)
        #pragma unroll
        for (int j = 0; j < 3; ++j)
          acc[i][j] = __builtin_amdgcn_mfma_f32_16x16x32_bf16(af[i], bfr[j], acc[i][j], 0, 0, 0);
    }
    __syncthreads();
  }
  const int em = (lane >> 4) * 4;
  const int en = lane & 15;
  const size_t pbase = (size_t)blockIdx.y * MROWS;
  #pragma unroll
  for (int i = 0; i < 2; ++i)
    #pragma unroll
    for (int j = 0; j < 3; ++j)
      #pragma unroll
      for (int r = 0; r < 4; ++r)
        Pw[(pbase + m0 + wr + i * 16 + em + r) * 48 + j * 16 + en] = acc[i][j][r];
}

// Kernel 3c: reduce 8 K-split partials + softmax gate -> Cb bf16 (128 blocks,
// coalesced; bit-identical per-column sp-order).
__global__ __launch_bounds__(256) void reduce_coeff(const float* __restrict__ Pw,
                                                    u16* __restrict__ Cb) {
  const int tid = threadIdx.x;
  const int rl = tid >> 2;
  const int cg = tid & 3;
  const int m = blockIdx.x * 64 + rl;
  const int lane = tid & 63;

  float s[12];
  #pragma unroll
  for (int q = 0; q < 12; ++q) s[q] = 0.f;
  for (int sp = 0; sp < 8; ++sp) {
    const float4* p = (const float4*)(Pw + ((size_t)sp * MROWS + m) * 48 + cg * 12);
    #pragma unroll
    for (int q = 0; q < 3; ++q) {
      float4 v = p[q];
      s[q * 4 + 0] += v.x; s[q * 4 + 1] += v.y;
      s[q * 4 + 2] += v.z; s[q * 4 + 3] += v.w;
    }
  }
  const int src = lane & ~3;
  const float L0 = __shfl(s[0], src);
  const float L1 = __shfl(s[1], src);
  const float L2 = __shfl(s[2], src);
  const float mx = fmaxf(L0, fmaxf(L1, L2));
  const float e0 = __expf(L0 - mx), e1 = __expf(L1 - mx), e2 = __expf(L2 - mx);
  const float inv = 1.f / (e0 + e1 + e2);
  const float om0 = e0 * inv, om1 = e1 * inv, om2 = e2 * inv;
  #pragma unroll
  for (int j = 0; j < 12; ++j) {
    const int G = cg * 12 + j;
    if (G >= 3 && G < 35) {
      const float wgt = (G < 11) ? om0 : (G < 19) ? om1 : (G < 27) ? om2 : 1.f;
      Cb[(size_t)m * 32 + (G - 3)] = f2bf(s[j] * wgt);
    }
  }
}

// ---------------------------------------------------------------------------
// Kernel 4: out = Xb @ Wb^T + Cb @ Ub^T.
// RESTORED to the 4-phase schedule (measured 232.9/234.4/234.7 us across
// rounds 1 & 4; 0 bank conflicts, MfmaUtil ~55%).
// REFUTED variants — do not retry:
//   * 32x32x16 MFMA in this packed layout (round 3): 25.4M conflict-cyc, 270 us.
//   * phase merge 4->2 (round 5): 248 us — fine per-phase interleave is the
//     lever (matches m196), not barrier amortization.

#define MF(a, b, c) __builtin_amdgcn_mfma_f32_16x16x32_bf16(a, b, c, 0, 0, 0)

#define MROW(A, I) \
  acc[I][0] = MF(A, bfr0, acc[I][0]); \
  acc[I][1] = MF(A, bfr1, acc[I][1]); \
  acc[I][2] = MF(A, bfr2, acc[I][2]); \
  acc[I][3] = MF(A, bfr3, acc[I][3]);

#define VM4 asm volatile("s_waitcnt vmcnt(4)" ::: "memory")
#define VM0 asm volatile("s_waitcnt vmcnt(0)" ::: "memory")

#define STA(REG, KOFF) { const u16* s_ = gA + (KOFF); \
  gl2lds16(s_, dA + (REG) * 8192); \
  gl2lds16(s_ + 128 * 4096, dA + (REG) * 8192 + 4096); }
#define STB(REG, KOFF) { const u16* s_ = gB + (KOFF); \
  gl2lds16(s_, dB + (REG) * 8192); \
  gl2lds16(s_ + 128 * 4096, dB + (REG) * 8192 + 4096); }
#define STC { const u16* s_ = Cb + (size_t)(m0 + gr1) * 32 + kc1; \
  gl2lds16(s_, dA); gl2lds16(s_ + 128 * 32, dA + 4096); }
#define STU { const u16* s_ = Ub + (size_t)(n0 + gr1) * 32 + kc1; \
  gl2lds16(s_, dB); gl2lds16(s_ + 128 * 32, dB + 4096); }

#define PH(REG, IH, LOADB, ISSUE, VMX) { \
  const u16* ap_ = sm + (REG) * 8192 + wmoff + (IH) * 2048 + off0; \
  bf16x8 af0 = *(const bf16x8*)(ap_); \
  bf16x8 af1 = *(const bf16x8*)(ap_ + 512); \
  bf16x8 af2 = *(const bf16x8*)(ap_ + 1024); \
  bf16x8 af3 = *(const bf16x8*)(ap_ + 1536); \
  if (LOADB) { \
    const u16* bp_ = sm + 32768 + (REG) * 8192 + wnoff + off0; \
    bfr0 = *(const bf16x8*)(bp_); \
    bfr1 = *(const bf16x8*)(bp_ + 512); \
    bfr2 = *(const bf16x8*)(bp_ + 1024); \
    bfr3 = *(const bf16x8*)(bp_ + 1536); \
  } \
  ISSUE; \
  asm volatile("" ::: "memory"); \
  __builtin_amdgcn_s_barrier(); \
  __builtin_amdgcn_s_setprio(1); \
  MROW(af0, (IH) * 4 + 0) \
  MROW(af1, (IH) * 4 + 1) \
  MROW(af2, (IH) * 4 + 2) \
  MROW(af3, (IH) * 4 + 3) \
  __builtin_amdgcn_s_setprio(0); \
  VMX; \
  asm volatile("" ::: "memory"); \
  __builtin_amdgcn_s_barrier(); \
}

#define TILE(B, I1, I2, I3, I4, VMX) { \
  bf16x8 bfr0, bfr1, bfr2, bfr3; \
  PH((B) * 2 + 0, 0, 1, I1, (void)0) \
  PH((B) * 2 + 0, 1, 0, I2, (void)0) \
  PH((B) * 2 + 1, 0, 1, I3, (void)0) \
  PH((B) * 2 + 1, 1, 0, I4, VMX) \
}

__global__ __launch_bounds__(512, 2) void gemm_fused8(
    const u16* __restrict__ Xb, const u16* __restrict__ Wb,
    const u16* __restrict__ Cb, const u16* __restrict__ Ub,
    float* __restrict__ out) {
  __shared__ __align__(16) u16 sm[65536];   // 128 KiB: A [0,32768), B [32768,65536)
  const int tid = threadIdx.x;
  const int bid = blockIdx.x;
  const int wg = (bid & 7) * 64 + (bid >> 3);   // XCD swizzle (nwg=512, 8|512)
  const int mt = wg >> 4;                        // 32 M-tiles
  const int nt = wg & 15;                        // 16 N-tiles
  const int m0 = mt * 256;
  const int n0 = nt * 256;
  const int lane = tid & 63;
  const int w = tid >> 6;
  const int wm = w >> 2;        // 0..1  (128 rows each)
  const int wn = w & 3;         // 0..3  (64 cols each)
  const int fm = lane & 15;
  const int qd = lane >> 4;
  const int off0 = (fm >> 1) * 64 + (((((fm & 1) << 2) | qd)) ^ (fm >> 1)) * 8;
  const int wmoff = wm * 4096;
  const int wnoff = wn * 2048;

  const int c1 = (tid & 7) ^ ((tid >> 3) & 7);
  const int gr1 = 2 * (tid >> 3) + (c1 >> 2);
  const int kc1 = (c1 & 3) * 8;
  const u16* gA = Xb + (size_t)(m0 + gr1) * 4096 + kc1;
  const u16* gB = Wb + (size_t)(n0 + gr1) * 4096 + kc1;
  u16* dA = sm + tid * 8;
  u16* dB = sm + 32768 + tid * 8;

  f32x4 acc[8][4];
  #pragma unroll
  for (int i = 0; i < 8; ++i)
    #pragma unroll
    for (int j = 0; j < 4; ++j) acc[i][j] = (f32x4){0.f, 0.f, 0.f, 0.f};

  // prologue: tile0 (regs 0,1), tile1 h0 (reg 2). vmcnt(4) leaves reg2 in flight.
  STA(0, 0)  STB(0, 0)
  STA(1, 32) STB(1, 32)
  STA(2, 64) STB(2, 64)
  VM4;
  asm volatile("" ::: "memory");
  __builtin_amdgcn_s_barrier();

  // main loop: tiles 0..61 (two per iteration). Issues per tile:
  // p1/p2 -> (T+1) K-half1; p3/p4 -> (T+2) K-half0.
  for (int T = 0; T < 62; T += 2) {
    TILE(0, STA(3, T * 64 + 96),  STB(3, T * 64 + 96),
            STA(0, T * 64 + 128), STB(0, T * 64 + 128), VM4)
    TILE(1, STA(1, T * 64 + 160), STB(1, T * 64 + 160),
            STA(2, T * 64 + 192), STB(2, T * 64 + 192), VM4)
  }
  // tile 62: issue tile63 h1; drain.
  TILE(0, STA(3, 4064), STB(3, 4064), (void)0, (void)0, VM0)
  // tile 63: issue LoRA stages (Cb->A reg0, Ub->B reg0); drain.
  TILE(1, STC, STU, (void)0, (void)0, VM0)

  // LoRA K=32 tail from regions A0/B0
  {
    const u16* ap = sm + wmoff + off0;
    const u16* bp = sm + 32768 + wnoff + off0;
    bf16x8 bfr0 = *(const bf16x8*)(bp);
    bf16x8 bfr1 = *(const bf16x8*)(bp + 512);
    bf16x8 bfr2 = *(const bf16x8*)(bp + 1024);
    bf16x8 bfr3 = *(const bf16x8*)(bp + 1536);
    #pragma unroll
    for (int i = 0; i < 8; ++i) {
      bf16x8 a = *(const bf16x8*)(ap + i * 512);
      acc[i][0] = MF(a, bfr0, acc[i][0]);
      acc[i][1] = MF(a, bfr1, acc[i][1]);
      acc[i][2] = MF(a, bfr2, acc[i][2]);
      acc[i][3] = MF(a, bfr3, acc[i][3]);
    }
  }

  // epilogue: C/D layout col=lane&15, row=(lane>>4)*4+reg
  const int em = qd * 4;
  const int en = fm;
  const size_t obase = (size_t)(m0 + wm * 128) * DOUT + n0 + wn * 64 + en;
  #pragma unroll
  for (int i = 0; i < 8; ++i)
    #pragma unroll
    for (int j = 0; j < 4; ++j)
      #pragma unroll
      for (int r = 0; r < 4; ++r)
        out[obase + (size_t)(i * 16 + em + r) * DOUT + j * 16] = acc[i][j][r];
}

// ---------------------------------------------------------------------------
extern "C" void kernel_launch(void* const* d_in, const int* in_sizes, int n_in,
                              void* d_out, int out_size, void* d_ws, size_t ws_size,
                              hipStream_t stream) {
  const float* x     = (const float*)d_in[0];  // [4,2048,4096]
  const float* W     = (const float*)d_in[1];  // [4096,4096]
  const float* down  = (const float*)d_in[2];  // [5,4096,8]
  const float* up    = (const float*)d_in[3];  // [5,8,4096]
  const float* route = (const float*)d_in[4];  // [5,4096,5]
  float* out = (float*)d_out;

  char* ws = (char*)d_ws;
  u16*   Xb = (u16*)ws;                        // 64 MiB
  u16*   Wb = (u16*)(ws + 67108864);           // 32 MiB
  u16*   Cb = (u16*)(ws + 100663296);          // 512 KiB
  u16*   Ub = (u16*)(ws + 101187584);          // 256 KiB
  u16*   Wt = (u16*)(ws + 101449728);          // 384 KiB
  float* Pw = (float*)(ws + 101842944);        // 12 MiB

  convx<<<32768, 256, 0, stream>>>(x, Xb);
  convw<<<16384, 256, 0, stream>>>(W, Wb);
  convu<<<16, 256, 0, stream>>>(up, Ub);
  wtprep<<<dim3(4, 48), 256, 0, stream>>>(route, down, Wt);
  coeffgemm<<<dim3(64, 8), 256, 0, stream>>>(Xb, Wt, Pw);
  reduce_coeff<<<128, 256, 0, stream>>>(Pw, Cb);
  gemm_fused8<<<512, 512, 0, stream>>>(Xb, Wb, Cb, Ub, out);
}

// Round 7
// 502.829 us; speedup vs baseline: 1.1500x; 1.0147x over previous
//
#include <hip/hip_runtime.h>
#include <hip/hip_bf16.h>

typedef unsigned short u16;
typedef __attribute__((ext_vector_type(8))) __bf16 bf16x8;
typedef __attribute__((ext_vector_type(4))) float f32x4;

#define DIN 4096
#define DOUT 4096
#define MROWS 8192

__device__ __forceinline__ u16 f2bf(float f) {
  unsigned int u = __float_as_uint(f);
  u += 0x7fffu + ((u >> 16) & 1u);   // RNE; inputs are finite randoms
  return (u16)(u >> 16);
}

__device__ __forceinline__ void gl2lds16(const void* g, void* l) {
  __builtin_amdgcn_global_load_lds(
      (const __attribute__((address_space(1))) unsigned int*)g,
      (__attribute__((address_space(3))) unsigned int*)l, 16, 0, 0);
}

// ---------------------------------------------------------------------------
// Prep chain: converged configuration (measured 3x: rounds 1/5/6).

// Kernel 0: x fp32 -> bf16
__global__ __launch_bounds__(256) void convx(const float* __restrict__ x,
                                             u16* __restrict__ Xb) {
  size_t i = ((size_t)blockIdx.x * 256 + threadIdx.x) * 4;
  float4 v = *(const float4*)(x + i);
  ushort4 o;
  o.x = f2bf(v.x); o.y = f2bf(v.y); o.z = f2bf(v.z); o.w = f2bf(v.w);
  *(ushort4*)(Xb + i) = o;
}

// Kernel 1: W fp32 -> bf16 (B^T layout is W's native [DOUT][DIN] layout)
__global__ __launch_bounds__(256) void convw(const float* __restrict__ W,
                                             u16* __restrict__ Wb) {
  size_t i = ((size_t)blockIdx.x * 256 + threadIdx.x) * 4;
  float4 v = *(const float4*)(W + i);
  ushort4 o;
  o.x = f2bf(v.x); o.y = f2bf(v.y); o.z = f2bf(v.z); o.w = f2bf(v.w);
  *(ushort4*)(Wb + i) = o;
}

// Kernel 2: Ub[n][c] = bf16(lora_up_flat[c][n]), c<32 (transpose)
__global__ __launch_bounds__(256) void convu(const float* __restrict__ up,
                                             u16* __restrict__ Ub) {
  int n = blockIdx.x * 256 + threadIdx.x;
  union { u16 us[32]; uint4 q[4]; } o;
  #pragma unroll
  for (int c = 0; c < 32; ++c) o.us[c] = f2bf(up[(size_t)c * DOUT + n]);
  uint4* dst = (uint4*)(Ub + (size_t)n * 32);
  #pragma unroll
  for (int q = 0; q < 4; ++q) dst[q] = o.q[q];
}

// Kernel 3a: pack coeff-GEMM weights Wt[48][4096] bf16.
__global__ __launch_bounds__(256) void wtprep(const float* __restrict__ route,
                                              const float* __restrict__ down,
                                              u16* __restrict__ Wt) {
  const int c = blockIdx.y;
  const int k0 = blockIdx.x * 1024 + threadIdx.x * 4;
  const float* route3 = route + 3 * DIN * 5;  // lora_route[3]
  float v[4];
  #pragma unroll
  for (int j = 0; j < 4; ++j) {
    int k = k0 + j;
    float f;
    if (c < 3)       f = route3[(size_t)k * 5 + c];
    else if (c < 35) f = down[(size_t)((c - 3) >> 3) * DIN * 8 + (size_t)k * 8 + ((c - 3) & 7)];
    else             f = 0.f;
    v[j] = f;
  }
  ushort4 o;
  o.x = f2bf(v[0]); o.y = f2bf(v[1]); o.z = f2bf(v[2]); o.w = f2bf(v[3]);
  *(ushort4*)(Wt + (size_t)c * DIN + k0) = o;
}

// Kernel 3b: MFMA tall-skinny GEMM Pw[split][8192][48] = Xb . Wt^T.
__global__ __launch_bounds__(256) void coeffgemm(
    const u16* __restrict__ Xb, const u16* __restrict__ Wt,
    float* __restrict__ Pw) {
  __shared__ __align__(16) u16 As[128 * 64];
  __shared__ __align__(16) u16 Bs[48 * 64];
  const int tid = threadIdx.x;
  const int m0 = blockIdx.x * 128;
  const int kb = blockIdx.y * 512;
  const int lane = tid & 63;
  const int w = tid >> 6;
  const int wr = w * 32;
  const int fm = lane & 15;
  const int xr = fm & 7;
  const int qd = lane >> 4;

  f32x4 acc[2][3];
  #pragma unroll
  for (int i = 0; i < 2; ++i)
    #pragma unroll
    for (int j = 0; j < 3; ++j) acc[i][j] = (f32x4){0.f, 0.f, 0.f, 0.f};

  const int srow = tid >> 3;                        // 0..31
  const int scol = ((tid & 7) ^ (srow & 7)) * 8;    // swizzled source chunk
  const u16* gA = Xb + (size_t)(m0 + srow) * DIN + kb + scol;
  u16* lA = As + tid * 8;

  for (int kc = 0; kc < 512; kc += 64) {
    gl2lds16(Wt + (size_t)srow * DIN + kb + kc + scol, Bs + tid * 8);
    if (tid < 128) {
      int u = 256 + tid;
      int usw = ((u & 7) ^ ((u >> 3) & 7)) * 8;
      gl2lds16(Wt + (size_t)(u >> 3) * DIN + kb + kc + usw, Bs + u * 8);
    }
    #pragma unroll
    for (int it = 0; it < 4; ++it)
      gl2lds16(gA + kc + (size_t)(it * 32) * DIN, lA + it * 2048);
    __syncthreads();
    #pragma unroll
    for (int kk = 0; kk < 64; kk += 32) {
      const int q = (kk >> 3) + qd;
      bf16x8 af[2], bfr[3];
      #pragma unroll
      for (int i = 0; i < 2; ++i)
        af[i] = *(const bf16x8*)(As + (wr + i * 16 + fm) * 64 + ((q ^ xr) << 3));
      #pragma unroll
      for (int j = 0; j < 3; ++j)
        bfr[j] = *(const bf16x8*)(Bs + (j * 16 + fm) * 64 + ((q ^ xr) << 3));
      #pragma unroll
      for (int i = 0; i < 2; ++i)
        #pragma unroll
        for (int j = 0; j < 3; ++j)
          acc[i][j] = __builtin_amdgcn_mfma_f32_16x16x32_bf16(af[i], bfr[j], acc[i][j], 0, 0, 0);
    }
    __syncthreads();
  }
  const int em = (lane >> 4) * 4;
  const int en = lane & 15;
  const size_t pbase = (size_t)blockIdx.y * MROWS;
  #pragma unroll
  for (int i = 0; i < 2; ++i)
    #pragma unroll
    for (int j = 0; j < 3; ++j)
      #pragma unroll
      for (int r = 0; r < 4; ++r)
        Pw[(pbase + m0 + wr + i * 16 + em + r) * 48 + j * 16 + en] = acc[i][j][r];
}

// Kernel 3c: reduce 8 K-split partials + softmax gate -> Cb bf16.
__global__ __launch_bounds__(256) void reduce_coeff(const float* __restrict__ Pw,
                                                    u16* __restrict__ Cb) {
  const int tid = threadIdx.x;
  const int rl = tid >> 2;
  const int cg = tid & 3;
  const int m = blockIdx.x * 64 + rl;
  const int lane = tid & 63;

  float s[12];
  #pragma unroll
  for (int q = 0; q < 12; ++q) s[q] = 0.f;
  for (int sp = 0; sp < 8; ++sp) {
    const float4* p = (const float4*)(Pw + ((size_t)sp * MROWS + m) * 48 + cg * 12);
    #pragma unroll
    for (int q = 0; q < 3; ++q) {
      float4 v = p[q];
      s[q * 4 + 0] += v.x; s[q * 4 + 1] += v.y;
      s[q * 4 + 2] += v.z; s[q * 4 + 3] += v.w;
    }
  }
  const int src = lane & ~3;
  const float L0 = __shfl(s[0], src);
  const float L1 = __shfl(s[1], src);
  const float L2 = __shfl(s[2], src);
  const float mx = fmaxf(L0, fmaxf(L1, L2));
  const float e0 = __expf(L0 - mx), e1 = __expf(L1 - mx), e2 = __expf(L2 - mx);
  const float inv = 1.f / (e0 + e1 + e2);
  const float om0 = e0 * inv, om1 = e1 * inv, om2 = e2 * inv;
  #pragma unroll
  for (int j = 0; j < 12; ++j) {
    const int G = cg * 12 + j;
    if (G >= 3 && G < 35) {
      const float wgt = (G < 11) ? om0 : (G < 19) ? om1 : (G < 27) ? om2 : 1.f;
      Cb[(size_t)m * 32 + (G - 3)] = f2bf(s[j] * wgt);
    }
  }
}

// ---------------------------------------------------------------------------
// Kernel 4: out = Xb @ Wb^T + Cb @ Ub^T.
// EXPERIMENT (in-window frag prefetch): phases now = {ISSUE gl2lds; barrier;
// [vmcnt]; window: 16 MFMA || ds_read next-phase frags (dbuf fA[2]/fB[2])}.
// Removes the serial pre-barrier ds_read segment (R5 showed serial-segment
// size is the lever); one barrier/phase. Ledger re-derived with reads one
// phase early: every region read lands >=5 loads behind its vmcnt(4);
// restage >=2 barriers after last read; concurrent-window regions disjoint
// for all 8 phase pairs; p4 vmcnt moved post-barrier/pre-window.
// K-order per acc unchanged -> bit-identical output.
// REFUTED — do not retry: 32x32x16 MFMA here (R3, +25M conflicts);
// 4->2 phase merge with serial reads (R5, -6%).

#define MF(a, b, c) __builtin_amdgcn_mfma_f32_16x16x32_bf16(a, b, c, 0, 0, 0)

#define MROW2(IH, I, BA, BB) \
  acc[(IH)*4+(I)][0] = MF(fA[BA][I], fB[BB][0], acc[(IH)*4+(I)][0]); \
  acc[(IH)*4+(I)][1] = MF(fA[BA][I], fB[BB][1], acc[(IH)*4+(I)][1]); \
  acc[(IH)*4+(I)][2] = MF(fA[BA][I], fB[BB][2], acc[(IH)*4+(I)][2]); \
  acc[(IH)*4+(I)][3] = MF(fA[BA][I], fB[BB][3], acc[(IH)*4+(I)][3]);

#define VM4 asm volatile("s_waitcnt vmcnt(4)" ::: "memory")
#define VM0 asm volatile("s_waitcnt vmcnt(0)" ::: "memory")

#define STA(REG, KOFF) { const u16* s_ = gA + (KOFF); \
  gl2lds16(s_, dA + (REG) * 8192); \
  gl2lds16(s_ + 128 * 4096, dA + (REG) * 8192 + 4096); }
#define STB(REG, KOFF) { const u16* s_ = gB + (KOFF); \
  gl2lds16(s_, dB + (REG) * 8192); \
  gl2lds16(s_ + 128 * 4096, dB + (REG) * 8192 + 4096); }
#define STC { const u16* s_ = Cb + (size_t)(m0 + gr1) * 32 + kc1; \
  gl2lds16(s_, dA); gl2lds16(s_ + 128 * 32, dA + 4096); }
#define STU { const u16* s_ = Ub + (size_t)(n0 + gr1) * 32 + kc1; \
  gl2lds16(s_, dB); gl2lds16(s_ + 128 * 32, dB + 4096); }

// One phase: ISSUE; barrier; VMX; window { prefetch next frags + 16 MFMA }.
//   IH: which acc row-half this phase computes (frags already in fA[BA],fB[BB])
//   PFA/PFB: 1 to prefetch next-phase A/B frags from region NREG into buf NBA/NBB
#define PHW(IH, BA, BB, PFA, NREG, NIH, NBA, PFB, NBB, ISSUE, VMX) { \
  ISSUE; \
  asm volatile("" ::: "memory"); \
  __builtin_amdgcn_s_barrier(); \
  asm volatile("" ::: "memory"); \
  VMX; \
  asm volatile("" ::: "memory"); \
  __builtin_amdgcn_s_setprio(1); \
  if (PFA) { \
    const u16* np_ = sm + (NREG) * 8192 + wmoff + (NIH) * 2048 + off0; \
    fA[NBA][0] = *(const bf16x8*)(np_); \
    fA[NBA][1] = *(const bf16x8*)(np_ + 512); \
    fA[NBA][2] = *(const bf16x8*)(np_ + 1024); \
    fA[NBA][3] = *(const bf16x8*)(np_ + 1536); \
  } \
  if (PFB) { \
    const u16* nb_ = sm + 32768 + (NREG) * 8192 + wnoff + off0; \
    fB[NBB][0] = *(const bf16x8*)(nb_); \
    fB[NBB][1] = *(const bf16x8*)(nb_ + 512); \
    fB[NBB][2] = *(const bf16x8*)(nb_ + 1024); \
    fB[NBB][3] = *(const bf16x8*)(nb_ + 1536); \
  } \
  MROW2(IH, 0, BA, BB) MROW2(IH, 1, BA, BB) \
  MROW2(IH, 2, BA, BB) MROW2(IH, 3, BA, BB) \
  __builtin_amdgcn_s_setprio(0); \
}

// One K-tile: regions R0 (K-half0), R1 (K-half1); R0N = next tile's K-half0.
// Buffer rotation: A per-phase 0,1,0,1; B per-pair 0,0,1,1 (period 2; 8 | 2).
#define TILEW(R0, R1, R0N, I1, I2, I3, I4, VMX4) { \
  PHW(0, 0, 0, 1, R0, 1, 1, 0, 0, I1, (void)0) \
  PHW(1, 1, 0, 1, R1, 0, 0, 1, 1, I2, (void)0) \
  PHW(0, 0, 1, 1, R1, 1, 1, 0, 0, I3, (void)0) \
  PHW(1, 1, 1, 1, R0N, 0, 0, 1, 0, I4, VMX4) \
}

__global__ __launch_bounds__(512, 2) void gemm_fused8(
    const u16* __restrict__ Xb, const u16* __restrict__ Wb,
    const u16* __restrict__ Cb, const u16* __restrict__ Ub,
    float* __restrict__ out) {
  __shared__ __align__(16) u16 sm[65536];   // 128 KiB: A [0,32768), B [32768,65536)
  const int tid = threadIdx.x;
  const int bid = blockIdx.x;
  const int wg = (bid & 7) * 64 + (bid >> 3);   // XCD swizzle (nwg=512, 8|512)
  const int mt = wg >> 4;                        // 32 M-tiles
  const int nt = wg & 15;                        // 16 N-tiles
  const int m0 = mt * 256;
  const int n0 = nt * 256;
  const int lane = tid & 63;
  const int w = tid >> 6;
  const int wm = w >> 2;        // 0..1  (128 rows each)
  const int wn = w & 3;         // 0..3  (64 cols each)
  const int fm = lane & 15;
  const int qd = lane >> 4;
  const int off0 = (fm >> 1) * 64 + (((((fm & 1) << 2) | qd)) ^ (fm >> 1)) * 8;
  const int wmoff = wm * 4096;
  const int wnoff = wn * 2048;

  const int c1 = (tid & 7) ^ ((tid >> 3) & 7);
  const int gr1 = 2 * (tid >> 3) + (c1 >> 2);
  const int kc1 = (c1 & 3) * 8;
  const u16* gA = Xb + (size_t)(m0 + gr1) * 4096 + kc1;
  const u16* gB = Wb + (size_t)(n0 + gr1) * 4096 + kc1;
  u16* dA = sm + tid * 8;
  u16* dB = sm + 32768 + tid * 8;

  f32x4 acc[8][4];
  #pragma unroll
  for (int i = 0; i < 8; ++i)
    #pragma unroll
    for (int j = 0; j < 4; ++j) acc[i][j] = (f32x4){0.f, 0.f, 0.f, 0.f};

  bf16x8 fA[2][4];
  bf16x8 fB[2][4];

  // prologue: stage regions 0,1,2; vmcnt(4) -> regions 0,1 landed; preload
  // first-phase frags (region 0, IH0) into fA[0]/fB[0].
  STA(0, 0)  STB(0, 0)
  STA(1, 32) STB(1, 32)
  STA(2, 64) STB(2, 64)
  VM4;
  asm volatile("" ::: "memory");
  __builtin_amdgcn_s_barrier();
  asm volatile("" ::: "memory");
  {
    const u16* pp = sm + wmoff + off0;
    fA[0][0] = *(const bf16x8*)(pp);
    fA[0][1] = *(const bf16x8*)(pp + 512);
    fA[0][2] = *(const bf16x8*)(pp + 1024);
    fA[0][3] = *(const bf16x8*)(pp + 1536);
    const u16* pb = sm + 32768 + wnoff + off0;
    fB[0][0] = *(const bf16x8*)(pb);
    fB[0][1] = *(const bf16x8*)(pb + 512);
    fB[0][2] = *(const bf16x8*)(pb + 1024);
    fB[0][3] = *(const bf16x8*)(pb + 1536);
  }

  // main loop: tiles 0..61. Per tile: p1/p2 issue (T+1)h1; p3/p4 issue (T+2)h0.
  for (int T = 0; T < 62; T += 2) {
    TILEW(0, 1, 2, STA(3, T * 64 + 96),  STB(3, T * 64 + 96),
                   STA(0, T * 64 + 128), STB(0, T * 64 + 128), VM4)
    TILEW(2, 3, 0, STA(1, T * 64 + 160), STB(1, T * 64 + 160),
                   STA(2, T * 64 + 192), STB(2, T * 64 + 192), VM4)
  }
  // tile 62: issue tile63 h1; drain (tile63 regions must be fully landed).
  TILEW(0, 1, 2, STA(3, 4064), STB(3, 4064), (void)0, (void)0, VM0)
  // tile 63: issue LoRA stages (Cb->A reg0, Ub->B reg0); drain. p4's dead
  // prefetch of region 0 is unused (DCE'd or harmless).
  TILEW(2, 3, 0, STC, STU, (void)0, (void)0, VM0)

  asm volatile("" ::: "memory");
  __builtin_amdgcn_s_barrier();
  asm volatile("" ::: "memory");

  // LoRA K=32 tail from regions A0/B0
  {
    const u16* ap = sm + wmoff + off0;
    const u16* bp = sm + 32768 + wnoff + off0;
    bf16x8 bfr0 = *(const bf16x8*)(bp);
    bf16x8 bfr1 = *(const bf16x8*)(bp + 512);
    bf16x8 bfr2 = *(const bf16x8*)(bp + 1024);
    bf16x8 bfr3 = *(const bf16x8*)(bp + 1536);
    #pragma unroll
    for (int i = 0; i < 8; ++i) {
      bf16x8 a = *(const bf16x8*)(ap + i * 512);
      acc[i][0] = MF(a, bfr0, acc[i][0]);
      acc[i][1] = MF(a, bfr1, acc[i][1]);
      acc[i][2] = MF(a, bfr2, acc[i][2]);
      acc[i][3] = MF(a, bfr3, acc[i][3]);
    }
  }

  // epilogue: C/D layout col=lane&15, row=(lane>>4)*4+reg
  const int em = qd * 4;
  const int en = fm;
  const size_t obase = (size_t)(m0 + wm * 128) * DOUT + n0 + wn * 64 + en;
  #pragma unroll
  for (int i = 0; i < 8; ++i)
    #pragma unroll
    for (int j = 0; j < 4; ++j)
      #pragma unroll
      for (int r = 0; r < 4; ++r)
        out[obase + (size_t)(i * 16 + em + r) * DOUT + j * 16] = acc[i][j][r];
}

// ---------------------------------------------------------------------------
extern "C" void kernel_launch(void* const* d_in, const int* in_sizes, int n_in,
                              void* d_out, int out_size, void* d_ws, size_t ws_size,
                              hipStream_t stream) {
  const float* x     = (const float*)d_in[0];  // [4,2048,4096]
  const float* W     = (const float*)d_in[1];  // [4096,4096]
  const float* down  = (const float*)d_in[2];  // [5,4096,8]
  const float* up    = (const float*)d_in[3];  // [5,8,4096]
  const float* route = (const float*)d_in[4];  // [5,4096,5]
  float* out = (float*)d_out;

  char* ws = (char*)d_ws;
  u16*   Xb = (u16*)ws;                        // 64 MiB
  u16*   Wb = (u16*)(ws + 67108864);           // 32 MiB
  u16*   Cb = (u16*)(ws + 100663296);          // 512 KiB
  u16*   Ub = (u16*)(ws + 101187584);          // 256 KiB
  u16*   Wt = (u16*)(ws + 101449728);          // 384 KiB
  float* Pw = (float*)(ws + 101842944);        // 12 MiB

  convx<<<32768, 256, 0, stream>>>(x, Xb);
  convw<<<16384, 256, 0, stream>>>(W, Wb);
  convu<<<16, 256, 0, stream>>>(up, Ub);
  wtprep<<<dim3(4, 48), 256, 0, stream>>>(route, down, Wt);
  coeffgemm<<<dim3(64, 8), 256, 0, stream>>>(Xb, Wt, Pw);
  reduce_coeff<<<128, 256, 0, stream>>>(Pw, Cb);
  gemm_fused8<<<512, 512, 0, stream>>>(Xb, Wb, Cb, Ub, out);
}